// Round 10
// baseline (11456.812 us; speedup 1.0000x reference)
//
#include <hip/hip_runtime.h>
#include <stdint.h>

// BiLSTM fused: B=64, T=1024, D=256, H=256/dir, O=64. In fp32, out fp32.
// Ledger: R19 @10.8ms (5.42ms/layer) best. Post-mortem: with wih in LDS, x
// prefetched, whh resident, late validate, the step chain arithmetic says
// 1.2-2.5k cy; observed 12.7k cy -> ~x4 unexplained multiplier on FABRIC
// legs, uniform across R15-R19 (every change moved time with leg COUNT, not
// estimated latency). R14's FMA heaters only falsified SCLK-DVFS; the
// memory/fabric clock (FCLK) governor sees 32 latency-bound WGs (~55GB/s) as
// idle and floors the fabric clock -> all L2/L3 RTTs x4. R20 probes this:
//   - real WGs: R19 byte-identical (grid slots bx<128, bx%8<2).
//   - 224 HEATER WGs: continuous agent-scope (sc-bit, cache-bypassing — the
//     exchange's own transaction class) 8B loads over an 8MB dead region of
//     d_out, paced by a short FMA chain (~500GB/s agg), exiting when the 32
//     real WGs bump a done counter (+ iteration backstop). R14 proved heater
//     co-residency is benign.
// Pre-registered: dur flat (+/-10%) while FETCH confirms heaters ran =>
// fabric-DVFS falsified, floor is genuine fabric latency for a 16-producer
// exchange; next round shrinks the exchange group instead.
//
// Structure: per layer, 2 dirs x 16 hidden-slices g; WG (dir,g) owns hidden
// cols j in [16g,16g+16) == gate rows {j,256+j,512+j,768+j}.
//   acc[gate] = bias + Wih @ x[t]^T + Whh @ h[t-1]^T      (D[j][b], fp32 acc)
// Exchange layout per dir: [1024 t][4 w][16 g][16 b_l][16 j_l] bf16 — slot
// (t,w,g) written by exactly one wave (512B); consumer wave (g*,w)'s step
// working set = slots (t,w,0..15) = 8KB contiguous. Sentinel 0xFF = bf16 NaN
// (gates clamped => |h|<1, f2bf never emits it).
//
// Memory plan: d_ws = h0 exch (64MB). x buf (d_in[0], fp32, 64MB, dead after
// layer-0) -> h1 bf16 (exact fit), 0xFF-filled between layers.
// d_out (16MB): [0,2MB) wb1=Wih_l1 bf16 | [2,3MB) wb0=Wih_l0 bf16 |
// [3MB,+256B) done counters | [4,12MB) heater scratch (dead). FC head runs
// last, overwrites all of d_out.

typedef __attribute__((ext_vector_type(8))) short short8;   // 8 x bf16
typedef __attribute__((ext_vector_type(4))) float floatx4;  // MFMA acc
typedef __attribute__((ext_vector_type(4))) float fx4;      // fp32 x loads

#define MFMA_BF16(A, B, C) __builtin_amdgcn_mfma_f32_16x16x32_bf16(A, B, C, 0, 0, 0)

__device__ __forceinline__ unsigned short f2bf(float f) {
  unsigned u = __float_as_uint(f);
  u += 0x7FFFu + ((u >> 16) & 1u);  // RNE
  return (unsigned short)(u >> 16);
}
__device__ __forceinline__ short8 load_cvt8(const float* p) {
  short8 r;
#pragma unroll
  for (int i = 0; i < 8; ++i) r[i] = (short)f2bf(p[i]);
  return r;
}
// NaN-killing clamps; inert for legit values (|gate preact| <~ 5, fc <~ 0.6).
__device__ __forceinline__ float clamp_gate(float x) { return fminf(30.f, fmaxf(-30.f, x)); }
__device__ __forceinline__ float clamp_fc(float x) { return fminf(4.f, fmaxf(-30.f, x)); }
__device__ __forceinline__ float sigm(float x) { return 1.0f / (1.0f + __expf(-x)); }
__device__ __forceinline__ float tanh_fast(float x) { return 1.0f - 2.0f / (1.0f + __expf(2.0f * x)); }

// 16B fragment valid iff no dword is all-ones.
__device__ __forceinline__ bool v16ok(short8 v) {
  const unsigned* d = (const unsigned*)&v;
  return (d[0] != 0xFFFFFFFFu) & (d[1] != 0xFFFFFFFFu) &
         (d[2] != 0xFFFFFFFFu) & (d[3] != 0xFFFFFFFFu);
}

// ---------------------------------------------------------------------------
// fp32 -> bf16 conversion (two regions), grid-strided.
// ---------------------------------------------------------------------------
__global__ __launch_bounds__(256) void cvt_kernel(
    const float* __restrict__ s0, unsigned short* __restrict__ d0, int n0,
    const float* __restrict__ s1, unsigned short* __restrict__ d1, int n1) {
  const int stride = gridDim.x * 256;
  for (int j = blockIdx.x * 256 + threadIdx.x; j < n0; j += stride) d0[j] = f2bf(s0[j]);
  for (int j = blockIdx.x * 256 + threadIdx.x; j < n1; j += stride) d1[j] = f2bf(s1[j]);
}

// ---------------------------------------------------------------------------
// One bidirectional LSTM layer, fused input GEMM + recurrence.
// LAYER=0: input = x fp32 [B][T][256] (prefetched fp32, cvt at consume).
// LAYER=1: input = h0 exch layout bf16 (K=512 concat of both dirs).
// wih+bias live in LDS; whh lives in VGPRs; x one step ahead in VGPRs.
// Grid 256: real WGs are bx<128 with bx%8<2 (dir=bx%8, g=bx>>3; XCD
// co-location under round-robin dispatch). ALL other WGs are fabric heaters.
// ---------------------------------------------------------------------------
template <int LAYER>
__global__ __launch_bounds__(256, 1) void lstm_layer_kernel(
    const float* __restrict__ xf32,          // LAYER 0 input
    const unsigned short* __restrict__ xbf,  // LAYER 1 input (h0, exch layout)
    const unsigned short* __restrict__ wih,  // bf16 [2][1024][KDIM]
    const float* __restrict__ WhhF, const float* __restrict__ WhhB,
    const float* __restrict__ bF, const float* __restrict__ bB,
    unsigned short* __restrict__ hout,       // exch layout [2][...]
    unsigned int* __restrict__ done,         // this layer's done counter line
    const unsigned long long* __restrict__ hscr) {  // 8MB heater scratch
  constexpr int NKS = LAYER ? 16 : 8;
  constexpr int KDIM = NKS * 32;
  constexpr size_t DIRSZ = (size_t)1024 * 16384;  // shorts per dir

  // wih fragments: [4 gi][NKS ks][64 lane][8 bf16]; bias: [64 lane][17 fp32].
  __shared__ short sw[4 * NKS * 64 * 8];
  __shared__ float sb[64 * 17];

  const int bx = blockIdx.x;
  const int slot = bx & 7;
  const int tid = threadIdx.x;
  const int w = tid >> 6, l = tid & 63, l15 = l & 15, q = l >> 4;

  // ---------------- FABRIC HEATER ----------------
  if (bx >= 128 || slot >= 2) {
    constexpr size_t NW = (8u << 20) / 8;  // 1M 8B words (pow2)
    unsigned long long acc = 0;
    float s0 = 0.5f + 0.001f * (float)tid;
    for (int blk = 0; blk < 200000; ++blk) {
#pragma unroll
      for (int i = 0; i < 8; ++i) {
        const size_t idx =
            (((size_t)bx << 14) + ((size_t)blk << 9) + ((size_t)tid << 3) + i) &
            (NW - 1);
        acc ^= __hip_atomic_load(hscr + idx, __ATOMIC_RELAXED,
                                 __HIP_MEMORY_SCOPE_AGENT);
      }
#pragma unroll
      for (int i = 0; i < 16; ++i) s0 = __builtin_fmaf(s0, 1.0000001f, 1e-9f);
      if ((blk & 63) == 0 &&
          __hip_atomic_load(done, __ATOMIC_RELAXED, __HIP_MEMORY_SCOPE_AGENT) >= 32u)
        break;
    }
    // Unreachable (keeps acc/s0 live without affecting real data).
    if (acc == 0xDEADBEEFDEADBEEFull && s0 == -1e30f && tid == 0) done[48] = 1u;
    return;
  }

  // ---------------- REAL LSTM WG (R19 byte-identical) ----------------
  const int dir = slot;
  const int g = bx >> 3;

  const float* Whh = dir ? WhhB : WhhF;
  const float* bias = dir ? bB : bF;

  // Stage wih fragments into LDS: wave w handles gate gi = w.
  const unsigned short* wd = wih + (size_t)dir * 1024 * KDIM;
#pragma unroll
  for (int ks = 0; ks < NKS; ++ks) {
    short8 v = *(const short8*)(wd + (size_t)(w * 256 + g * 16 + l15) * KDIM +
                                ks * 32 + q * 8);
    *(short8*)(sw + ((size_t)(w * NKS + ks) * 64 + l) * 8) = v;
  }
  // Stage per-lane bias (depends on l only; wave 0 covers all lanes).
  if (w == 0) {
#pragma unroll
    for (int gi = 0; gi < 4; ++gi)
#pragma unroll
      for (int r = 0; r < 4; ++r)
        sb[l * 17 + gi * 4 + r] = bias[gi * 256 + g * 16 + (l >> 4) * 4 + r];
  }

  // Whh A-fragments resident: cvt fp32 -> bf16 (lane l15 -> j-row, q -> kq).
  short8 whh[4][8];
#pragma unroll
  for (int gi = 0; gi < 4; ++gi) {
    const float* wr = Whh + (size_t)(gi * 256 + g * 16 + l15) * 256;
#pragma unroll
    for (int ks = 0; ks < 8; ++ks) whh[gi][ks] = load_cvt8(wr + ks * 32 + q * 8);
  }
  __syncthreads();

  const int b = w * 16 + l15;  // batch index this lane feeds (B-fragment)
  unsigned short* hd = hout + (size_t)dir * DIRSZ;

  float c[4] = {0.f, 0.f, 0.f, 0.f};

  // x prefetch buffers (one step ahead). L0: raw fp32 (cvt at consume, keeps
  // the loads async); L1: bf16 fragments. Static indexing (reg-resident).
  fx4 xn0[LAYER ? 1 : 8][2];
  short8 xn1[LAYER ? 16 : 1];

  auto issue_prefetch = [&](int tt) {
    if (LAYER == 0) {
#pragma unroll
      for (int ks = 0; ks < 8; ++ks) {
        const float* p = xf32 + (((size_t)b << 10) + tt) * 256 + ks * 32 + q * 8;
        xn0[ks][0] = *(const fx4*)p;
        xn0[ks][1] = *(const fx4*)(p + 4);
      }
    } else {
#pragma unroll
      for (int ks = 0; ks < 16; ++ks) {
        const int k = ks * 32 + q * 8;
        const int gp = (k & 255) >> 4;  // = (ks&7)*2 + (q>>1)
        const size_t off = (size_t)(k >> 8) * DIRSZ +
                           (((size_t)tt * 4 + w) * 16 + gp) * 256 + l15 * 16 +
                           (k & 15);
        xn1[ks] = *(const short8*)(xbf + off);
      }
    }
  };

  issue_prefetch(dir ? 1023 : 0);  // prologue: x for it=0

  for (int it = 0; it < 1024; ++it) {
    const int t = dir ? (1023 - it) : it;
    const int tp = dir ? (t + 1) : (t - 1);
    const int tn = dir ? (t > 0 ? t - 1 : 0) : (t < 1023 ? t + 1 : 1023);

    const unsigned short* hbase = hd + ((size_t)tp * 4 + w) * (16 * 256);
    const int sub = l15 * 16 + (q & 1) * 8;  // shorts within a slot-pair

    // ---- (1) PEEK issue: plain coalesced b128 loads (L2 fast path).
    short8 pk[8];
    if (it > 0) {
#pragma unroll
      for (int ks = 0; ks < 8; ++ks)
        pk[ks] = *(const short8*)(hbase + (size_t)(ks * 2 + (q >> 1)) * 256 + sub);
    }

    // ---- (2) acc init + x-MFMAs from PREFETCHED regs (zero-wait) ----
    floatx4 acc[4];
#pragma unroll
    for (int gi = 0; gi < 4; ++gi) acc[gi] = *(const floatx4*)(sb + l * 17 + gi * 4);

#pragma unroll
    for (int ks = 0; ks < NKS; ++ks) {
      short8 xf;
      if (LAYER == 0) {
#pragma unroll
        for (int i = 0; i < 4; ++i) xf[i] = (short)f2bf(xn0[ks][0][i]);
#pragma unroll
        for (int i = 0; i < 4; ++i) xf[4 + i] = (short)f2bf(xn0[ks][1][i]);
      } else {
        xf = xn1[ks];
      }
#pragma unroll
      for (int gi = 0; gi < 4; ++gi) {
        const short8 wf = *(const short8*)(sw + ((size_t)(gi * NKS + ks) * 64 + l) * 8);
        acc[gi] = MFMA_BF16(wf, xf, acc[gi]);
      }
    }

    // ---- (3) issue NEXT step's x prefetch (lands under validate+h+gates) ----
    issue_prefetch(tn);

    if (it > 0) {
      // ---- (4) validate peek; fallback agent-scope re-poll ----
      bool ok = true;
#pragma unroll
      for (int ks = 0; ks < 8; ++ks) ok = ok & v16ok(pk[ks]);
      while (!__all(ok)) {
#pragma unroll
        for (int ks = 0; ks < 8; ++ks) {
          if (!v16ok(pk[ks])) {
            const unsigned long long* p = (const unsigned long long*)(
                hbase + (size_t)(ks * 2 + (q >> 1)) * 256 + sub);
            unsigned long long lo =
                __hip_atomic_load(p, __ATOMIC_RELAXED, __HIP_MEMORY_SCOPE_AGENT);
            unsigned long long hi =
                __hip_atomic_load(p + 1, __ATOMIC_RELAXED, __HIP_MEMORY_SCOPE_AGENT);
            short8 v;
            ((unsigned long long*)&v)[0] = lo;
            ((unsigned long long*)&v)[1] = hi;
            pk[ks] = v;
          }
        }
        ok = true;
#pragma unroll
        for (int ks = 0; ks < 8; ++ks) ok = ok & v16ok(pk[ks]);
      }

      // ---- (5) h-part MFMAs: pure register compute (whh resident) ----
#pragma unroll
      for (int ks = 0; ks < 8; ++ks) {
#pragma unroll
        for (int gi = 0; gi < 4; ++gi) acc[gi] = MFMA_BF16(whh[gi][ks], pk[ks], acc[gi]);
      }
    }

    // ---- (6) gates (i,f,g,o all in this lane) ----
    unsigned long long hv = 0ull;
#pragma unroll
    for (int r = 0; r < 4; ++r) {
      const float si = sigm(clamp_gate(acc[0][r]));
      const float sf = sigm(clamp_gate(acc[1][r]));
      const float tg = tanh_fast(clamp_gate(acc[2][r]));
      const float so = sigm(clamp_gate(acc[3][r]));
      const float cn = sf * c[r] + si * tg;
      c[r] = cn;
      const unsigned short hb16 = f2bf(so * tanh_fast(cn));
      hv |= ((unsigned long long)hb16) << (16 * r);
    }

    // ---- (7) DUAL PUBLISH: volatile plain store (local-XCD L2 fast path) +
    //      agent-scope write-through store (L3 safety copy). ----
    unsigned long long* dst =
        (unsigned long long*)(hd + (((size_t)t * 4 + w) * 16 + g) * 256 +
                              l15 * 16 + q * 4);
    *(volatile unsigned long long*)dst = hv;
    __hip_atomic_store(dst, hv, __ATOMIC_RELAXED, __HIP_MEMORY_SCOPE_AGENT);
  }

  // Signal heaters: this real WG is done.
  if (tid == 0)
    __hip_atomic_fetch_add(done, 1u, __ATOMIC_RELAXED, __HIP_MEMORY_SCOPE_AGENT);
}

// ---------------------------------------------------------------------------
// FC head: out[b][t][o] = exp(h1concat[t][b][:] @ fc_W[o][:]^T + fc_b[o])
// h1 is in exch layout. fc_W fp32 -> bf16 into LDS once per block. Grid 1024
// x 256thr; block covers 64 rows (m = b*1024+t). OUTPUT FP32.
// ---------------------------------------------------------------------------
__global__ __launch_bounds__(256) void fc_head_kernel(
    const unsigned short* __restrict__ h1,  // exch layout [2][...] bf16
    const float* __restrict__ fcW,          // [64][512] fp32
    const float* __restrict__ fcb,          // [64] fp32
    float* __restrict__ out) {              // [B][T][64] fp32
  constexpr size_t DIRSZ = (size_t)1024 * 16384;
  __shared__ unsigned short sW[64 * 512];
  const int tid = threadIdx.x;
  for (int i = tid; i < 64 * 512; i += 256) sW[i] = f2bf(fcW[i]);
  __syncthreads();

  const int w = tid >> 6, l = tid & 63, l15 = l & 15, q = l >> 4;
  const int m0 = blockIdx.x * 64 + w * 16;

  const int mA = m0 + l15;
  const int bA = mA >> 10, tA = mA & 1023;
  // Lane's A-row base within a dir: [tA][w'=bA>>4][g'][b_l=bA&15][j_l].
  const size_t arow = ((size_t)tA * 4 + (bA >> 4)) * (16 * 256) +
                      (size_t)(bA & 15) * 16 + (q & 1) * 8;

  floatx4 acc[4];
#pragma unroll
  for (int nt = 0; nt < 4; ++nt) acc[nt] = (floatx4){0.f, 0.f, 0.f, 0.f};

#pragma unroll
  for (int dh = 0; dh < 2; ++dh) {
    const unsigned short* ad = h1 + (size_t)dh * DIRSZ;
#pragma unroll
    for (int ks = 0; ks < 8; ++ks) {
      const int gp = ks * 2 + (q >> 1);
      short8 af = *(const short8*)(ad + arow + (size_t)gp * 256);
#pragma unroll
      for (int nt = 0; nt < 4; ++nt) {
        short8 bf = *(const short8*)(sW + (nt * 16 + l15) * 512 + dh * 256 +
                                     ks * 32 + q * 8);
        acc[nt] = MFMA_BF16(af, bf, acc[nt]);
      }
    }
  }

#pragma unroll
  for (int nt = 0; nt < 4; ++nt) {
    const float bv = fcb[nt * 16 + l15];
#pragma unroll
    for (int r = 0; r < 4; ++r) {
      const int m = m0 + q * 4 + r;
      out[(size_t)m * 64 + nt * 16 + l15] = __expf(clamp_fc(acc[nt][r] + bv));
    }
  }
}

// ---------------------------------------------------------------------------
__global__ void diag_kernel(float* out, int n, float code) {
  int i = blockIdx.x * 256 + threadIdx.x;
  if (i < n) out[i] = (i == 0) ? code : 1.0f;
}

// ---------------------------------------------------------------------------

extern "C" void kernel_launch(void* const* d_in, const int* in_sizes, int n_in,
                              void* d_out, int out_size, void* d_ws, size_t ws_size,
                              hipStream_t stream) {
  const float* x       = (const float*)d_in[0];
  const float* Wih_l0f = (const float*)d_in[1];
  const float* Whh_l0f = (const float*)d_in[2];
  const float* b_l0f   = (const float*)d_in[3];
  const float* Wih_l0b = (const float*)d_in[4];
  const float* Whh_l0b = (const float*)d_in[5];
  const float* b_l0b   = (const float*)d_in[6];
  const float* Wih_l1f = (const float*)d_in[7];
  const float* Whh_l1f = (const float*)d_in[8];
  const float* b_l1f   = (const float*)d_in[9];
  const float* Wih_l1b = (const float*)d_in[10];
  const float* Whh_l1b = (const float*)d_in[11];
  const float* b_l1b   = (const float*)d_in[12];
  const float* fc_W    = (const float*)d_in[13];
  const float* fc_b    = (const float*)d_in[14];
  float* out = (float*)d_out;

  const size_t H_BYTES = (size_t)2 * 1024 * 64 * 256 * 2;  // 64MB

  if (ws_size < H_BYTES) {
    diag_kernel<<<dim3((out_size + 255) / 256), dim3(256), 0, stream>>>(
        out, out_size, 200.0f + (float)(ws_size >> 20));
    return;
  }

  unsigned short* h0 = (unsigned short*)d_ws;     // exch layout, 64MB
  unsigned short* h1 = (unsigned short*)d_in[0];  // x buf (fp32, 64MB): dead
                                                  // after layer-0 -> h1 bf16
  // d_out: wb1 [0,2MB) | wb0 [2,3MB) | done ctrs @3MB | heater scratch [4,12MB).
  unsigned short* wb1 = (unsigned short*)d_out;
  unsigned short* wb0 = (unsigned short*)((uint8_t*)d_out + (2u << 20));
  unsigned int* done  = (unsigned int*)((uint8_t*)d_out + (3u << 20));
  const unsigned long long* hscr =
      (const unsigned long long*)((uint8_t*)d_out + (4u << 20));

  // Sentinel-fill h0 (h1 is filled after layer-0 frees the x buffer).
  hipMemsetAsync(h0, 0xFF, H_BYTES, stream);
  hipMemsetAsync(done, 0, 256, stream);  // done[0..31]=layer0, done[32..]=layer1

  // Wih fp32 -> bf16 into d_out's dead prefix.
  cvt_kernel<<<dim3(512), dim3(256), 0, stream>>>(
      Wih_l1f, wb1, 1024 * 512, Wih_l1b, wb1 + (size_t)1024 * 512, 1024 * 512);
  cvt_kernel<<<dim3(512), dim3(256), 0, stream>>>(
      Wih_l0f, wb0, 1024 * 256, Wih_l0b, wb0 + (size_t)1024 * 256, 1024 * 256);

  lstm_layer_kernel<0><<<dim3(256), dim3(256), 0, stream>>>(
      x, nullptr, wb0, Whh_l0f, Whh_l0b, b_l0f, b_l0b, h0, done, hscr);
  hipMemsetAsync(h1, 0xFF, H_BYTES, stream);  // stream-ordered after layer-0
  lstm_layer_kernel<1><<<dim3(256), dim3(256), 0, stream>>>(
      nullptr, h0, wb1, Whh_l1f, Whh_l1b, b_l1f, b_l1b, h1, done + 32, hscr);
  fc_head_kernel<<<dim3(1024), dim3(256), 0, stream>>>(h1, fc_W, fc_b, out);
}